// Round 4
// baseline (1278.222 us; speedup 1.0000x reference)
//
#include <hip/hip_runtime.h>
#include <stdint.h>

typedef unsigned short u16;
typedef uint32_t u32;
typedef short bf16x8 __attribute__((ext_vector_type(8)));
typedef float f32x4 __attribute__((ext_vector_type(4)));

#define DEV_INLINE __device__ __forceinline__

DEV_INLINE float b2f(u16 u) { union { u32 u; float f; } a; a.u = ((u32)u) << 16; return a.f; }
DEV_INLINE u16 f2b(float f) {
    union { float f; u32 u; } a; a.f = f;
    u32 u = a.u;
    u += 0x7fffu + ((u >> 16) & 1u);
    return (u16)(u >> 16);
}

typedef __attribute__((address_space(1))) u32 as1_u32;
typedef __attribute__((address_space(3))) u32 as3_u32;
DEV_INLINE void async16(void* lds, const void* g) {
    __builtin_amdgcn_global_load_lds((as1_u32*)g, (as3_u32*)lds, 16, 0, 0);
}

// ---------------------------------------------------------------------------
// Generic batched bf16 GEMM: C[z] = A[z] (M,K) @ B[z]^T, B stored (N,K) row-major.
// MODE 0: fp32 store. MODE 1: bf16 store.
// ---------------------------------------------------------------------------
template <int MODE>
__global__ __launch_bounds__(256) void gemm_bt(
    const u16* __restrict__ Ab, const u16* __restrict__ Bb, void* __restrict__ Cv,
    int K, long lda, long ldb, long ldc,
    long zA1, long zA2, long zB1, long zB2, long zC1, long zC2)
{
    __shared__ __align__(16) u16 As[128 * 32];
    __shared__ __align__(16) u16 Bs[128 * 32];

    const int z = blockIdx.z;
    const long zb = z >> 5, zh = z & 31;
    const u16* A = Ab + zb * zA1 + zh * zA2;
    const u16* B = Bb + zb * zB1 + zh * zB2;

    const int tid = threadIdx.x;
    const int w = tid >> 6, l = tid & 63;
    const int quad = l >> 4, lrow = l & 15;
    const int wm = w & 1, wn = w >> 1;
    const long row0 = (long)blockIdx.y * 128;
    const long col0 = (long)blockIdx.x * 128;

    f32x4 acc[4][4];
#pragma unroll
    for (int mi = 0; mi < 4; mi++)
#pragma unroll
        for (int ni = 0; ni < 4; ni++) {
            f32x4 zv = {0.f, 0.f, 0.f, 0.f};
            acc[mi][ni] = zv;
        }

    const u16* gA = A + (row0 + w * 16 + (l >> 2)) * lda + (l & 3) * 8;
    const u16* gB = B + (col0 + w * 16 + (l >> 2)) * ldb + (l & 3) * 8;
    u16* lA = &As[(w * 16) * 32];
    u16* lB = &Bs[(w * 16) * 32];
    const long a64 = 64 * lda, b64 = 64 * ldb;

    const int nk = K >> 5;
    for (int kt = 0; kt < nk; ++kt) {
        __syncthreads();
        async16(lA, gA);
        async16(lA + 64 * 32, gA + a64);
        async16(lB, gB);
        async16(lB + 64 * 32, gB + b64);
        gA += 32;
        gB += 32;
        __syncthreads();

        bf16x8 af[4], bfr[4];
#pragma unroll
        for (int i = 0; i < 4; i++)
            af[i] = *(const bf16x8*)&As[(wm * 64 + i * 16 + lrow) * 32 + quad * 8];
#pragma unroll
        for (int i = 0; i < 4; i++)
            bfr[i] = *(const bf16x8*)&Bs[(wn * 64 + i * 16 + lrow) * 32 + quad * 8];
#pragma unroll
        for (int mi = 0; mi < 4; mi++)
#pragma unroll
            for (int ni = 0; ni < 4; ni++)
                acc[mi][ni] = __builtin_amdgcn_mfma_f32_16x16x32_bf16(af[mi], bfr[ni], acc[mi][ni], 0, 0, 0);
    }

    const long crow = row0 + wm * 64 + quad * 4;
    const long ccol = col0 + wn * 64 + lrow;
    float* Cf = (float*)Cv + zb * zC1 + zh * zC2;
    u16* Cb = (u16*)Cv + zb * zC1 + zh * zC2;
#pragma unroll
    for (int mi = 0; mi < 4; mi++)
#pragma unroll
        for (int rr = 0; rr < 4; rr++) {
            const long r = crow + mi * 16 + rr;
#pragma unroll
            for (int ni = 0; ni < 4; ni++) {
                const long c = ccol + ni * 16;
                const float v = acc[mi][ni][rr];
                if constexpr (MODE == 0) Cf[r * ldc + c] = v;
                else Cb[r * ldc + c] = f2b(v);
            }
        }
}

// ---------------------------------------------------------------------------
// Fused causal flash attention.
// Block: (qt = blockIdx.x in [0,32), z = blockIdx.z = b*32+h). TQ=32, TK=64.
// qcat (2048,32,576) A-side; kcat (2048,576) K-side; kvt (2,512,1024) V^T;
// o1 (2048,32,512) output.
// Wave w: S cols [w*16,w*16+16), O cols [w*128,(w+1)*128).
// ---------------------------------------------------------------------------
__global__ __launch_bounds__(256) void flash_attn(
    const u16* __restrict__ qcat, const u16* __restrict__ kcat,
    const u16* __restrict__ kvt, u16* __restrict__ o1)
{
    const int qt = blockIdx.x;
    const int z = blockIdx.z;
    const int b = z >> 5, h = z & 31;
    const int tid = threadIdx.x;
    const int w = tid >> 6, l = tid & 63;
    const int quad = l >> 4, lrow = l & 15;

    __shared__ __align__(16) u16 Qs[32 * 584];     // pitch 584: +4 banks/row
    __shared__ __align__(16) u16 Ps[32 * 72];      // pitch 72
    __shared__ __align__(16) float redm[32][4];
    __shared__ __align__(16) float redl[32][4];

    // ---- load Q tile (rows qt*32..+32, head h) into LDS ----
    // 32 rows x 72 bf16x8-chunks = 2304 chunks, 9 iterations per thread
    {
        const long base = (((long)b * 1024 + (long)qt * 32) * 32 + h) * 576;
        for (int i = tid; i < 2304; i += 256) {
            const int r = i / 72, c = i % 72;
            bf16x8 v = *(const bf16x8*)(qcat + base + (long)r * 18432 + c * 8);
            *(bf16x8*)&Qs[r * 584 + c * 8] = v;
        }
    }

    float mrun[8], lrun[8];
#pragma unroll
    for (int i = 0; i < 8; i++) { mrun[i] = -1e30f; lrun[i] = 0.f; }
    f32x4 oacc[2][8];
#pragma unroll
    for (int mi = 0; mi < 2; mi++)
#pragma unroll
        for (int ni = 0; ni < 8; ni++) {
            f32x4 zv = {0.f, 0.f, 0.f, 0.f};
            oacc[mi][ni] = zv;
        }

    const float SL = 0.0721687836487032f * 1.4426950408889634f;  // SCALE*log2(e)
    const int nkt = (qt >> 1) + 1;
    const u16* Kb = kcat + (long)b * 1024 * 576 + (w * 16 + lrow) * 576 + quad * 8;
    const u16* Vb = kvt + (long)b * 512 * 1024 + (w * 128 + lrow) * 1024 + quad * 8;
    const int qr = qt * 32 + quad * 4;  // + mi*16 + rr = this lane's S/O rows

    for (int kt = 0; kt < nkt; kt++) {
        __syncthreads();  // protects Qs(first iter), Ps/redm/redl reuse

        // ---- S = Q·K^T (this wave's 16 cols), K frags straight from L2 ----
        f32x4 s0 = {0.f, 0.f, 0.f, 0.f}, s1 = {0.f, 0.f, 0.f, 0.f};
        const u16* kp = Kb + (long)kt * 64 * 576;
#pragma unroll 6
        for (int kc = 0; kc < 18; kc++) {
            bf16x8 bk = *(const bf16x8*)(kp + kc * 32);
            bf16x8 a0 = *(const bf16x8*)&Qs[lrow * 584 + kc * 32 + quad * 8];
            bf16x8 a1 = *(const bf16x8*)&Qs[(16 + lrow) * 584 + kc * 32 + quad * 8];
            s0 = __builtin_amdgcn_mfma_f32_16x16x32_bf16(a0, bk, s0, 0, 0, 0);
            s1 = __builtin_amdgcn_mfma_f32_16x16x32_bf16(a1, bk, s1, 0, 0, 0);
        }

        // ---- scale + causal mask, log2 domain ----
        const int tc = kt * 64 + w * 16 + lrow;
        float sv[8];
#pragma unroll
        for (int rr = 0; rr < 4; rr++) {
            sv[rr] = (tc > qr + rr) ? -1e30f : s0[rr] * SL;
            sv[4 + rr] = (tc > qr + 16 + rr) ? -1e30f : s1[rr] * SL;
        }

        // ---- wave-local col max (over 16 lrow lanes) ----
        float mx[8];
#pragma unroll
        for (int i = 0; i < 8; i++) mx[i] = sv[i];
#pragma unroll
        for (int d = 1; d < 16; d <<= 1)
#pragma unroll
            for (int i = 0; i < 8; i++) mx[i] = fmaxf(mx[i], __shfl_xor(mx[i], d));
        if (lrow == 0) {
#pragma unroll
            for (int i = 0; i < 8; i++)
                redm[(i >> 2) * 16 + quad * 4 + (i & 3)][w] = mx[i];
        }
        __syncthreads();

        float alpha[8], mnew[8];
#pragma unroll
        for (int i = 0; i < 8; i++) {
            const int row = (i >> 2) * 16 + quad * 4 + (i & 3);
            f32x4 r4 = *(const f32x4*)&redm[row][0];
            const float mk = fmaxf(fmaxf(r4[0], r4[1]), fmaxf(r4[2], r4[3]));
            mnew[i] = fmaxf(mrun[i], mk);
            alpha[i] = exp2f(mrun[i] - mnew[i]);
            mrun[i] = mnew[i];
        }
        float p[8];
#pragma unroll
        for (int i = 0; i < 8; i++) p[i] = exp2f(sv[i] - mnew[i]);
        // P -> LDS (bf16), C/D layout -> row-major
#pragma unroll
        for (int i = 0; i < 8; i++)
            Ps[((i >> 2) * 16 + quad * 4 + (i & 3)) * 72 + w * 16 + lrow] = f2b(p[i]);
        // row-sum partials
        float sm[8];
#pragma unroll
        for (int i = 0; i < 8; i++) sm[i] = p[i];
#pragma unroll
        for (int d = 1; d < 16; d <<= 1)
#pragma unroll
            for (int i = 0; i < 8; i++) sm[i] += __shfl_xor(sm[i], d);
        if (lrow == 0) {
#pragma unroll
            for (int i = 0; i < 8; i++)
                redl[(i >> 2) * 16 + quad * 4 + (i & 3)][w] = sm[i];
        }
        __syncthreads();  // covers Ps writes and redl writes

#pragma unroll
        for (int i = 0; i < 8; i++) {
            const int row = (i >> 2) * 16 + quad * 4 + (i & 3);
            f32x4 r4 = *(const f32x4*)&redl[row][0];
            lrun[i] = lrun[i] * alpha[i] + (r4[0] + r4[1] + r4[2] + r4[3]);
        }
#pragma unroll
        for (int mi = 0; mi < 2; mi++)
#pragma unroll
            for (int ni = 0; ni < 8; ni++)
#pragma unroll
                for (int rr = 0; rr < 4; rr++)
                    oacc[mi][ni][rr] *= alpha[mi * 4 + rr];

        // ---- PV: O += P·V, V^T frags straight from kvt (L2) ----
        const u16* vp0 = Vb + kt * 64;
#pragma unroll
        for (int ks = 0; ks < 2; ks++) {
            bf16x8 pa0 = *(const bf16x8*)&Ps[lrow * 72 + ks * 32 + quad * 8];
            bf16x8 pa1 = *(const bf16x8*)&Ps[(16 + lrow) * 72 + ks * 32 + quad * 8];
#pragma unroll
            for (int ni = 0; ni < 8; ni++) {
                bf16x8 vb = *(const bf16x8*)(vp0 + ni * 16 * 1024 + ks * 32);
                oacc[0][ni] = __builtin_amdgcn_mfma_f32_16x16x32_bf16(pa0, vb, oacc[0][ni], 0, 0, 0);
                oacc[1][ni] = __builtin_amdgcn_mfma_f32_16x16x32_bf16(pa1, vb, oacc[1][ni], 0, 0, 0);
            }
        }
    }

    // ---- epilogue: normalize, store o1[((b*1024+qt*32+row)*32+h)*512 + col] ----
    float inv[8];
#pragma unroll
    for (int i = 0; i < 8; i++) inv[i] = 1.0f / lrun[i];
    const long obase = (((long)b * 1024 + (long)qt * 32) * 32 + h) * 512;
#pragma unroll
    for (int mi = 0; mi < 2; mi++)
#pragma unroll
        for (int rr = 0; rr < 4; rr++) {
            const int row = mi * 16 + quad * 4 + rr;
#pragma unroll
            for (int ni = 0; ni < 8; ni++) {
                const int col = w * 128 + ni * 16 + lrow;
                o1[obase + (long)row * 16384 + col] = f2b(oacc[mi][ni][rr] * inv[mi * 4 + rr]);
            }
        }
}

// ---------------------------------------------------------------------------
DEV_INLINE float ldval(const float* p) { return *p; }
DEV_INLINE float ldval(const u16* p) { return b2f(*p); }

template <typename SRC>
__global__ __launch_bounds__(256) void transpose_b16(
    const SRC* __restrict__ src, u16* __restrict__ dst,
    int R, int C, long ldS, long ldD, long zS, long zD)
{
    __shared__ float t[32][33];
    src += (long)blockIdx.z * zS;
    dst += (long)blockIdx.z * zD;
    const int tx = threadIdx.x & 31, ty = threadIdx.x >> 5;
    const long c0 = (long)blockIdx.x * 32, r0 = (long)blockIdx.y * 32;
#pragma unroll
    for (int i = 0; i < 4; i++) {
        long r = r0 + ty + i * 8, c = c0 + tx;
        if (r < R && c < C) t[ty + i * 8][tx] = ldval(&src[r * ldS + c]);
    }
    __syncthreads();
#pragma unroll
    for (int i = 0; i < 4; i++) {
        long c = c0 + ty + i * 8, r = r0 + tx;
        if (r < R && c < C) dst[c * ldD + r] = f2b(t[tx][ty + i * 8]);
    }
}

__global__ __launch_bounds__(256) void conv_b16(
    const float* __restrict__ src, u16* __restrict__ dst,
    int C, long ldS, long ldD, long zS, long zD)
{
    const long r = blockIdx.x;
    const float* s = src + (long)blockIdx.z * zS + r * ldS;
    u16* d = dst + (long)blockIdx.z * zD + r * ldD;
    for (int c = threadIdx.x; c < C; c += 256) d[c] = f2b(s[c]);
}

__global__ __launch_bounds__(256) void rmsnorm_b16(
    const float* __restrict__ X, const float* __restrict__ W, u16* __restrict__ Y,
    int C, long ldx, long ldy)
{
    const long r = blockIdx.x;
    const float* x = X + r * ldx;
    u16* y = Y + r * ldy;
    float ss = 0.f;
    for (int c = threadIdx.x; c < C; c += 256) { float v = x[c]; ss += v * v; }
    for (int off = 32; off; off >>= 1) ss += __shfl_down(ss, off);
    __shared__ float red[4];
    if ((threadIdx.x & 63) == 0) red[threadIdx.x >> 6] = ss;
    __syncthreads();
    const float tot = red[0] + red[1] + red[2] + red[3];
    const float inv = rsqrtf(tot / (float)C + 1e-6f);
    for (int c = threadIdx.x; c < C; c += 256) y[c] = f2b(x[c] * inv * W[c]);
}

__global__ __launch_bounds__(256) void rope_k_kernel(
    const float* __restrict__ kv, const float* __restrict__ fc, u16* __restrict__ kcat)
{
    const int idx = blockIdx.x * 256 + threadIdx.x;
    const int n = idx >> 5, i = idx & 31;
    const int s = n & 1023;
    const float e = kv[(long)n * 640 + 512 + 2 * i];
    const float o = kv[(long)n * 640 + 512 + 2 * i + 1];
    const float cs = fc[s * 64 + 2 * i], sn = fc[s * 64 + 2 * i + 1];
    kcat[(long)n * 576 + 512 + 2 * i] = f2b(e * cs - o * sn);
    kcat[(long)n * 576 + 512 + 2 * i + 1] = f2b(e * sn + o * cs);
}

__global__ __launch_bounds__(256) void rope_q_kernel(
    const u16* __restrict__ q, const float* __restrict__ fc, u16* __restrict__ qcat)
{
    const long idx = (long)blockIdx.x * 256 + threadIdx.x;
    const int i = (int)(idx & 31);
    const long nh = idx >> 5;
    const int h = (int)(nh & 31);
    const long n = nh >> 5;
    const int s = (int)(n & 1023);
    const float e = b2f(q[n * 6144 + h * 192 + 128 + 2 * i]);
    const float o = b2f(q[n * 6144 + h * 192 + 128 + 2 * i + 1]);
    const float cs = fc[s * 64 + 2 * i], sn = fc[s * 64 + 2 * i + 1];
    qcat[n * 18432 + h * 576 + 512 + 2 * i] = f2b(e * cs - o * sn);
    qcat[n * 18432 + h * 576 + 512 + 2 * i + 1] = f2b(e * sn + o * cs);
}

__global__ void sentinel_kernel(float* out, float v) { out[0] = v; }

// ---------------------------------------------------------------------------
extern "C" void kernel_launch(void* const* d_in, const int* in_sizes, int n_in,
                              void* d_out, int out_size, void* d_ws, size_t ws_size,
                              hipStream_t stream)
{
    const float* x = (const float*)d_in[0];
    const float* fc = (const float*)d_in[1];
    const float* wq_a = (const float*)d_in[3];
    const float* qnw = (const float*)d_in[4];
    const float* wq_b = (const float*)d_in[5];
    const float* wkva = (const float*)d_in[6];
    const float* kvnw = (const float*)d_in[7];
    const float* wkvb = (const float*)d_in[8];
    const float* wo = (const float*)d_in[9];
    float* out = (float*)d_out;

    const size_t NEED = 251920384ULL;
    if (ws_size < NEED) {
        sentinel_kernel<<<1, 1, 0, stream>>>(out, (float)ws_size);
        return;
    }
    char* ws = (char*)d_ws;
    u16* wkbv   = (u16*)(ws + 0);            // (32,128,512)
    u16* wo_t   = (u16*)(ws + 4194304);      // (4096,4096)
    u16* kvn_t  = (u16*)(ws + 37748736);     // (2,512,1024)
    u16* kcat   = (u16*)(ws + 39845888);     // (2048,576)
    u16* qcat   = (u16*)(ws + 42205184);     // (2048,32,576) live s3..flash
    // early buffers (dead before flash):
    u16*   xb     = (u16*)(ws + 117702656);  // (2048,4096)
    u16*   wq_a_t = (u16*)(ws + 134479872);  // (1536,4096)
    u16*   wq_b_t = (u16*)(ws + 147062784);  // (6144,1536)
    u16*   wkva_t = (u16*)(ws + 165937152);  // (640,4096)
    u16*   wkbn_t = (u16*)(ws + 171180032);  // (32,512,128)
    float* q_lat  = (float*)(ws + 175374336);// (2048,1536) fp32
    float* kvf    = (float*)(ws + 187957248);// (2048,640) fp32
    u16*   qn     = (u16*)(ws + 193200128);  // (2048,1536)
    u16*   q      = (u16*)(ws + 199491584);  // (2048,6144)
    // late buffers (overlay early region; qcat must NOT alias o1):
    u16* o1 = (u16*)(ws + 117702656);        // (2048,32,512) 67,108,864
    u16* o2 = (u16*)(ws + 184811520);        // (2048,4096)   16,777,216 -> 201,588,736

    const dim3 blk(256);

    // ---- weight prep ----
    transpose_b16<float><<<dim3(48, 128, 1), blk, 0, stream>>>(wq_a, wq_a_t, 4096, 1536, 1536, 4096, 0, 0);
    transpose_b16<float><<<dim3(192, 48, 1), blk, 0, stream>>>(wq_b, wq_b_t, 1536, 6144, 6144, 1536, 0, 0);
    transpose_b16<float><<<dim3(18, 128, 1), blk, 0, stream>>>(wkva, wkva_t, 4096, 576, 576, 4096, 0, 0);
    transpose_b16<float><<<dim3(16, 4, 32), blk, 0, stream>>>(wkvb, wkbn_t, 128, 512, 512, 128, 256 * 512, 512 * 128);
    conv_b16<<<dim3(128, 1, 32), blk, 0, stream>>>(wkvb + 128 * 512, wkbv, 512, 512, 512, 256 * 512, 128 * 512);
    transpose_b16<float><<<dim3(128, 128, 1), blk, 0, stream>>>(wo, wo_t, 4096, 4096, 4096, 4096, 0, 0);
    conv_b16<<<dim3(2048, 1, 1), blk, 0, stream>>>(x, xb, 4096, 4096, 4096, 0, 0);

    // ---- s1: latent projections ----
    gemm_bt<0><<<dim3(12, 16, 1), blk, 0, stream>>>(xb, wq_a_t, q_lat, 4096, 4096, 4096, 1536,
                                                    0, 0, 0, 0, 0, 0);
    gemm_bt<0><<<dim3(5, 16, 1), blk, 0, stream>>>(xb, wkva_t, kvf, 4096, 4096, 4096, 640,
                                                   0, 0, 0, 0, 0, 0);
    // ---- norms + rope_k + kv transpose ----
    rmsnorm_b16<<<2048, blk, 0, stream>>>(q_lat, qnw, qn, 1536, 1536, 1536);
    rmsnorm_b16<<<2048, blk, 0, stream>>>(kvf, kvnw, kcat, 512, 640, 576);
    rope_k_kernel<<<256, blk, 0, stream>>>(kvf, fc, kcat);
    transpose_b16<u16><<<dim3(16, 32, 2), blk, 0, stream>>>(kcat, kvn_t, 1024, 512, 576, 1024,
                                                            (long)1024 * 576, (long)512 * 1024);
    // ---- s2: q = qn @ wq_b^T ----
    gemm_bt<1><<<dim3(48, 16, 1), blk, 0, stream>>>(qn, wq_b_t, q, 1536, 1536, 1536, 6144,
                                                    0, 0, 0, 0, 0, 0);
    // ---- s3: q_abs per head + rope_q -> qcat ----
    gemm_bt<1><<<dim3(4, 16, 32), blk, 0, stream>>>(q, wkbn_t, qcat, 128, 6144, 128, 18432,
                                                    0, 192, 0, (long)512 * 128, 0, 576);
    rope_q_kernel<<<8192, blk, 0, stream>>>(q, fc, qcat);
    // ---- fused causal flash attention: qcat,kcat,kvn_t -> o1 ----
    flash_attn<<<dim3(32, 1, 64), blk, 0, stream>>>(qcat, kcat, kvn_t, o1);
    // ---- s6: o2 = o1 @ wkv_b_v^T per head ----
    gemm_bt<1><<<dim3(1, 16, 32), blk, 0, stream>>>(o1, wkbv, o2, 512, 16384, 512, 4096,
                                                    0, 512, 0, (long)128 * 512, 0, 128);
    // ---- s7: out = o2 @ wo^T ----
    gemm_bt<0><<<dim3(32, 16, 1), blk, 0, stream>>>(o2, wo_t, out, 4096, 4096, 4096, 4096,
                                                    0, 0, 0, 0, 0, 0);
    (void)in_sizes; (void)n_in; (void)out_size; (void)d_in;
}

// Round 5
// 1189.682 us; speedup vs baseline: 1.0744x; 1.0744x over previous
//
#include <hip/hip_runtime.h>
#include <stdint.h>

typedef unsigned short u16;
typedef uint32_t u32;
typedef short bf16x8 __attribute__((ext_vector_type(8)));
typedef float f32x4 __attribute__((ext_vector_type(4)));

#define DEV_INLINE __device__ __forceinline__

DEV_INLINE float b2f(u16 u) { union { u32 u; float f; } a; a.u = ((u32)u) << 16; return a.f; }
DEV_INLINE u16 f2b(float f) {
    union { float f; u32 u; } a; a.f = f;
    u32 u = a.u;
    u += 0x7fffu + ((u >> 16) & 1u);
    return (u16)(u >> 16);
}

typedef __attribute__((address_space(1))) u32 as1_u32;
typedef __attribute__((address_space(3))) u32 as3_u32;
DEV_INLINE void async16(void* lds, const void* g) {
    __builtin_amdgcn_global_load_lds((as1_u32*)g, (as3_u32*)lds, 16, 0, 0);
}

// ---------------------------------------------------------------------------
// Generic batched bf16 GEMM: C[z] = A[z] (M,K) @ B[z]^T, B stored (N,K) row-major.
// MODE 0: fp32 store. MODE 1: bf16 store.
// ---------------------------------------------------------------------------
template <int MODE>
__global__ __launch_bounds__(256) void gemm_bt(
    const u16* __restrict__ Ab, const u16* __restrict__ Bb, void* __restrict__ Cv,
    int K, long lda, long ldb, long ldc,
    long zA1, long zA2, long zB1, long zB2, long zC1, long zC2)
{
    __shared__ __align__(16) u16 As[128 * 32];
    __shared__ __align__(16) u16 Bs[128 * 32];

    const int z = blockIdx.z;
    const long zb = z >> 5, zh = z & 31;
    const u16* A = Ab + zb * zA1 + zh * zA2;
    const u16* B = Bb + zb * zB1 + zh * zB2;

    const int tid = threadIdx.x;
    const int w = tid >> 6, l = tid & 63;
    const int quad = l >> 4, lrow = l & 15;
    const int wm = w & 1, wn = w >> 1;
    const long row0 = (long)blockIdx.y * 128;
    const long col0 = (long)blockIdx.x * 128;

    f32x4 acc[4][4];
#pragma unroll
    for (int mi = 0; mi < 4; mi++)
#pragma unroll
        for (int ni = 0; ni < 4; ni++) {
            f32x4 zv = {0.f, 0.f, 0.f, 0.f};
            acc[mi][ni] = zv;
        }

    const u16* gA = A + (row0 + w * 16 + (l >> 2)) * lda + (l & 3) * 8;
    const u16* gB = B + (col0 + w * 16 + (l >> 2)) * ldb + (l & 3) * 8;
    u16* lA = &As[(w * 16) * 32];
    u16* lB = &Bs[(w * 16) * 32];
    const long a64 = 64 * lda, b64 = 64 * ldb;

    const int nk = K >> 5;
    for (int kt = 0; kt < nk; ++kt) {
        __syncthreads();
        async16(lA, gA);
        async16(lA + 64 * 32, gA + a64);
        async16(lB, gB);
        async16(lB + 64 * 32, gB + b64);
        gA += 32;
        gB += 32;
        __syncthreads();

        bf16x8 af[4], bfr[4];
#pragma unroll
        for (int i = 0; i < 4; i++)
            af[i] = *(const bf16x8*)&As[(wm * 64 + i * 16 + lrow) * 32 + quad * 8];
#pragma unroll
        for (int i = 0; i < 4; i++)
            bfr[i] = *(const bf16x8*)&Bs[(wn * 64 + i * 16 + lrow) * 32 + quad * 8];
#pragma unroll
        for (int mi = 0; mi < 4; mi++)
#pragma unroll
            for (int ni = 0; ni < 4; ni++)
                acc[mi][ni] = __builtin_amdgcn_mfma_f32_16x16x32_bf16(af[mi], bfr[ni], acc[mi][ni], 0, 0, 0);
    }

    const long crow = row0 + wm * 64 + quad * 4;
    const long ccol = col0 + wn * 64 + lrow;
    float* Cf = (float*)Cv + zb * zC1 + zh * zC2;
    u16* Cb = (u16*)Cv + zb * zC1 + zh * zC2;
#pragma unroll
    for (int mi = 0; mi < 4; mi++)
#pragma unroll
        for (int rr = 0; rr < 4; rr++) {
            const long r = crow + mi * 16 + rr;
#pragma unroll
            for (int ni = 0; ni < 4; ni++) {
                const long c = ccol + ni * 16;
                const float v = acc[mi][ni][rr];
                if constexpr (MODE == 0) Cf[r * ldc + c] = v;
                else Cb[r * ldc + c] = f2b(v);
            }
        }
}

// ---------------------------------------------------------------------------
// Fused causal flash attention, v2: 512 threads (8 waves), TQ=32, TK=128.
// Block: (qt = 31-blockIdx.x [LPT], z = blockIdx.z = b*32+h).
// Wave w in [0,8): S cols [w*16,(w+1)*16), O cols [w*64,(w+1)*64).
// qcat (2048,32,576); kcat (2048,576); kvt (2,512,1024) = V^T; o1 (2048,32,512).
// ---------------------------------------------------------------------------
__global__ __launch_bounds__(512, 4) void flash_attn(
    const u16* __restrict__ qcat, const u16* __restrict__ kcat,
    const u16* __restrict__ kvt, u16* __restrict__ o1)
{
    const int qt = 31 - (int)blockIdx.x;  // LPT: longest blocks launch first
    const int z = blockIdx.z;
    const int b = z >> 5, h = z & 31;
    const int tid = threadIdx.x;
    const int w = tid >> 6, l = tid & 63;
    const int quad = l >> 4, lrow = l & 15;

    __shared__ __align__(16) u16 Qs[32 * 584];     // 37,376 B (pitch 584)
    __shared__ __align__(16) u16 Ps[32 * 136];     //  8,704 B (pitch 136)
    __shared__ __align__(16) float redm[32][8];    //  1,024 B
    __shared__ __align__(16) float redl[32][8];    //  1,024 B

    // ---- load Q tile: 32 rows x 72 chunks = 2304 bf16x8 chunks ----
    {
        const long base = (((long)b * 1024 + (long)qt * 32) * 32 + h) * 576;
        for (int i = tid; i < 2304; i += 512) {
            const int r = i / 72, c = i % 72;
            *(bf16x8*)&Qs[r * 584 + c * 8] = *(const bf16x8*)(qcat + base + (long)r * 18432 + c * 8);
        }
    }

    float mrun[8], lrun[8];
#pragma unroll
    for (int i = 0; i < 8; i++) { mrun[i] = -1e30f; lrun[i] = 0.f; }
    f32x4 oacc[2][4];
#pragma unroll
    for (int mi = 0; mi < 2; mi++)
#pragma unroll
        for (int ni = 0; ni < 4; ni++) {
            f32x4 zv = {0.f, 0.f, 0.f, 0.f};
            oacc[mi][ni] = zv;
        }

    const float SL = 0.0721687836487032f * 1.4426950408889634f;  // SCALE*log2(e)
    const int nkt = (qt >> 2) + 1;
    const u16* Kb = kcat + (long)b * 1024 * 576 + (w * 16 + lrow) * 576 + quad * 8;
    const u16* Vb = kvt + (long)b * 512 * 1024 + (w * 64 + lrow) * 1024 + quad * 8;
    const int qr = qt * 32 + quad * 4;  // + mi*16 + rr = this lane's S/O rows

    for (int kt = 0; kt < nkt; kt++) {
        __syncthreads();  // protects Qs(first iter) and Ps/red reuse

        // ---- S = Q·K^T: wave w covers keys kt*128 + w*16 + lrow ----
        f32x4 s0 = {0.f, 0.f, 0.f, 0.f}, s1 = {0.f, 0.f, 0.f, 0.f};
        const u16* kp = Kb + (long)kt * 128 * 576;
#pragma unroll 6
        for (int kc = 0; kc < 18; kc++) {
            bf16x8 bk = *(const bf16x8*)(kp + kc * 32);
            bf16x8 a0 = *(const bf16x8*)&Qs[lrow * 584 + kc * 32 + quad * 8];
            bf16x8 a1 = *(const bf16x8*)&Qs[(16 + lrow) * 584 + kc * 32 + quad * 8];
            s0 = __builtin_amdgcn_mfma_f32_16x16x32_bf16(a0, bk, s0, 0, 0, 0);
            s1 = __builtin_amdgcn_mfma_f32_16x16x32_bf16(a1, bk, s1, 0, 0, 0);
        }

        // ---- scale + causal mask (log2 domain) ----
        const int tc = kt * 128 + w * 16 + lrow;
        float sv[8];
#pragma unroll
        for (int rr = 0; rr < 4; rr++) {
            sv[rr] = (tc > qr + rr) ? -1e30f : s0[rr] * SL;
            sv[4 + rr] = (tc > qr + 16 + rr) ? -1e30f : s1[rr] * SL;
        }

        // ---- wave-local column max over 16 lrow lanes ----
        float mx[8];
#pragma unroll
        for (int i = 0; i < 8; i++) mx[i] = sv[i];
#pragma unroll
        for (int d = 1; d < 16; d <<= 1)
#pragma unroll
            for (int i = 0; i < 8; i++) mx[i] = fmaxf(mx[i], __shfl_xor(mx[i], d));
        if (lrow == 0) {
#pragma unroll
            for (int i = 0; i < 8; i++)
                redm[(i >> 2) * 16 + quad * 4 + (i & 3)][w] = mx[i];
        }
        __syncthreads();

        float alpha[8], mnew[8];
#pragma unroll
        for (int i = 0; i < 8; i++) {
            const int row = (i >> 2) * 16 + quad * 4 + (i & 3);
            f32x4 ra = *(const f32x4*)&redm[row][0];
            f32x4 rb = *(const f32x4*)&redm[row][4];
            float mk = fmaxf(fmaxf(fmaxf(ra[0], ra[1]), fmaxf(ra[2], ra[3])),
                             fmaxf(fmaxf(rb[0], rb[1]), fmaxf(rb[2], rb[3])));
            mnew[i] = fmaxf(mrun[i], mk);
            alpha[i] = exp2f(mrun[i] - mnew[i]);
            mrun[i] = mnew[i];
        }
        float p[8];
#pragma unroll
        for (int i = 0; i < 8; i++) p[i] = exp2f(sv[i] - mnew[i]);
        // P -> LDS (bf16), C/D layout -> row-major
#pragma unroll
        for (int i = 0; i < 8; i++)
            Ps[((i >> 2) * 16 + quad * 4 + (i & 3)) * 136 + w * 16 + lrow] = f2b(p[i]);
        // row-sum partials
        float sm[8];
#pragma unroll
        for (int i = 0; i < 8; i++) sm[i] = p[i];
#pragma unroll
        for (int d = 1; d < 16; d <<= 1)
#pragma unroll
            for (int i = 0; i < 8; i++) sm[i] += __shfl_xor(sm[i], d);
        if (lrow == 0) {
#pragma unroll
            for (int i = 0; i < 8; i++)
                redl[(i >> 2) * 16 + quad * 4 + (i & 3)][w] = sm[i];
        }
        __syncthreads();  // covers Ps and redl writes

#pragma unroll
        for (int i = 0; i < 8; i++) {
            const int row = (i >> 2) * 16 + quad * 4 + (i & 3);
            f32x4 ra = *(const f32x4*)&redl[row][0];
            f32x4 rb = *(const f32x4*)&redl[row][4];
            lrun[i] = lrun[i] * alpha[i] +
                      (ra[0] + ra[1] + ra[2] + ra[3] + rb[0] + rb[1] + rb[2] + rb[3]);
        }
#pragma unroll
        for (int mi = 0; mi < 2; mi++)
#pragma unroll
            for (int ni = 0; ni < 4; ni++)
#pragma unroll
                for (int rr = 0; rr < 4; rr++)
                    oacc[mi][ni][rr] *= alpha[mi * 4 + rr];

        // ---- PV: O += P·V over 128 keys; V^T frags straight from L2 ----
        const u16* vp0 = Vb + kt * 128;
#pragma unroll
        for (int ks = 0; ks < 4; ks++) {
            bf16x8 pa0 = *(const bf16x8*)&Ps[lrow * 136 + ks * 32 + quad * 8];
            bf16x8 pa1 = *(const bf16x8*)&Ps[(16 + lrow) * 136 + ks * 32 + quad * 8];
#pragma unroll
            for (int ni = 0; ni < 4; ni++) {
                bf16x8 vb = *(const bf16x8*)(vp0 + ni * 16 * 1024 + ks * 32);
                oacc[0][ni] = __builtin_amdgcn_mfma_f32_16x16x32_bf16(pa0, vb, oacc[0][ni], 0, 0, 0);
                oacc[1][ni] = __builtin_amdgcn_mfma_f32_16x16x32_bf16(pa1, vb, oacc[1][ni], 0, 0, 0);
            }
        }
    }

    // ---- epilogue: normalize, store o1 ----
    float inv[8];
#pragma unroll
    for (int i = 0; i < 8; i++) inv[i] = 1.0f / lrun[i];
    const long obase = (((long)b * 1024 + (long)qt * 32) * 32 + h) * 512;
#pragma unroll
    for (int mi = 0; mi < 2; mi++)
#pragma unroll
        for (int rr = 0; rr < 4; rr++) {
            const int row = mi * 16 + quad * 4 + rr;
#pragma unroll
            for (int ni = 0; ni < 4; ni++) {
                const int col = w * 64 + ni * 16 + lrow;
                o1[obase + (long)row * 16384 + col] = f2b(oacc[mi][ni][rr] * inv[mi * 4 + rr]);
            }
        }
}

// ---------------------------------------------------------------------------
DEV_INLINE float ldval(const float* p) { return *p; }
DEV_INLINE float ldval(const u16* p) { return b2f(*p); }

template <typename SRC>
__global__ __launch_bounds__(256) void transpose_b16(
    const SRC* __restrict__ src, u16* __restrict__ dst,
    int R, int C, long ldS, long ldD, long zS, long zD)
{
    __shared__ float t[32][33];
    src += (long)blockIdx.z * zS;
    dst += (long)blockIdx.z * zD;
    const int tx = threadIdx.x & 31, ty = threadIdx.x >> 5;
    const long c0 = (long)blockIdx.x * 32, r0 = (long)blockIdx.y * 32;
#pragma unroll
    for (int i = 0; i < 4; i++) {
        long r = r0 + ty + i * 8, c = c0 + tx;
        if (r < R && c < C) t[ty + i * 8][tx] = ldval(&src[r * ldS + c]);
    }
    __syncthreads();
#pragma unroll
    for (int i = 0; i < 4; i++) {
        long c = c0 + ty + i * 8, r = r0 + tx;
        if (r < R && c < C) dst[c * ldD + r] = f2b(t[tx][ty + i * 8]);
    }
}

__global__ __launch_bounds__(256) void conv_b16(
    const float* __restrict__ src, u16* __restrict__ dst,
    int C, long ldS, long ldD, long zS, long zD)
{
    const long r = blockIdx.x;
    const float* s = src + (long)blockIdx.z * zS + r * ldS;
    u16* d = dst + (long)blockIdx.z * zD + r * ldD;
    for (int c = threadIdx.x; c < C; c += 256) d[c] = f2b(s[c]);
}

__global__ __launch_bounds__(256) void rmsnorm_b16(
    const float* __restrict__ X, const float* __restrict__ W, u16* __restrict__ Y,
    int C, long ldx, long ldy)
{
    const long r = blockIdx.x;
    const float* x = X + r * ldx;
    u16* y = Y + r * ldy;
    float ss = 0.f;
    for (int c = threadIdx.x; c < C; c += 256) { float v = x[c]; ss += v * v; }
    for (int off = 32; off; off >>= 1) ss += __shfl_down(ss, off);
    __shared__ float red[4];
    if ((threadIdx.x & 63) == 0) red[threadIdx.x >> 6] = ss;
    __syncthreads();
    const float tot = red[0] + red[1] + red[2] + red[3];
    const float inv = rsqrtf(tot / (float)C + 1e-6f);
    for (int c = threadIdx.x; c < C; c += 256) y[c] = f2b(x[c] * inv * W[c]);
}

__global__ __launch_bounds__(256) void rope_k_kernel(
    const float* __restrict__ kv, const float* __restrict__ fc, u16* __restrict__ kcat)
{
    const int idx = blockIdx.x * 256 + threadIdx.x;
    const int n = idx >> 5, i = idx & 31;
    const int s = n & 1023;
    const float e = kv[(long)n * 640 + 512 + 2 * i];
    const float o = kv[(long)n * 640 + 512 + 2 * i + 1];
    const float cs = fc[s * 64 + 2 * i], sn = fc[s * 64 + 2 * i + 1];
    kcat[(long)n * 576 + 512 + 2 * i] = f2b(e * cs - o * sn);
    kcat[(long)n * 576 + 512 + 2 * i + 1] = f2b(e * sn + o * cs);
}

__global__ __launch_bounds__(256) void rope_q_kernel(
    const u16* __restrict__ q, const float* __restrict__ fc, u16* __restrict__ qcat)
{
    const long idx = (long)blockIdx.x * 256 + threadIdx.x;
    const int i = (int)(idx & 31);
    const long nh = idx >> 5;
    const int h = (int)(nh & 31);
    const long n = nh >> 5;
    const int s = (int)(n & 1023);
    const float e = b2f(q[n * 6144 + h * 192 + 128 + 2 * i]);
    const float o = b2f(q[n * 6144 + h * 192 + 128 + 2 * i + 1]);
    const float cs = fc[s * 64 + 2 * i], sn = fc[s * 64 + 2 * i + 1];
    qcat[n * 18432 + h * 576 + 512 + 2 * i] = f2b(e * cs - o * sn);
    qcat[n * 18432 + h * 576 + 512 + 2 * i + 1] = f2b(e * sn + o * cs);
}

__global__ void sentinel_kernel(float* out, float v) { out[0] = v; }

// ---------------------------------------------------------------------------
extern "C" void kernel_launch(void* const* d_in, const int* in_sizes, int n_in,
                              void* d_out, int out_size, void* d_ws, size_t ws_size,
                              hipStream_t stream)
{
    const float* x = (const float*)d_in[0];
    const float* fc = (const float*)d_in[1];
    const float* wq_a = (const float*)d_in[3];
    const float* qnw = (const float*)d_in[4];
    const float* wq_b = (const float*)d_in[5];
    const float* wkva = (const float*)d_in[6];
    const float* kvnw = (const float*)d_in[7];
    const float* wkvb = (const float*)d_in[8];
    const float* wo = (const float*)d_in[9];
    float* out = (float*)d_out;

    const size_t NEED = 251920384ULL;
    if (ws_size < NEED) {
        sentinel_kernel<<<1, 1, 0, stream>>>(out, (float)ws_size);
        return;
    }
    char* ws = (char*)d_ws;
    u16* wkbv   = (u16*)(ws + 0);            // (32,128,512)
    u16* wo_t   = (u16*)(ws + 4194304);      // (4096,4096)
    u16* kvn_t  = (u16*)(ws + 37748736);     // (2,512,1024)
    u16* kcat   = (u16*)(ws + 39845888);     // (2048,576)
    u16* qcat   = (u16*)(ws + 42205184);     // (2048,32,576) live s3..flash
    // early buffers (dead before flash):
    u16*   xb     = (u16*)(ws + 117702656);  // (2048,4096)
    u16*   wq_a_t = (u16*)(ws + 134479872);  // (1536,4096)
    u16*   wq_b_t = (u16*)(ws + 147062784);  // (6144,1536)
    u16*   wkva_t = (u16*)(ws + 165937152);  // (640,4096)
    u16*   wkbn_t = (u16*)(ws + 171180032);  // (32,512,128)
    float* q_lat  = (float*)(ws + 175374336);// (2048,1536) fp32
    float* kvf    = (float*)(ws + 187957248);// (2048,640) fp32
    u16*   qn     = (u16*)(ws + 193200128);  // (2048,1536)
    u16*   q      = (u16*)(ws + 199491584);  // (2048,6144)
    // late buffers (overlay early region; qcat must NOT alias o1):
    u16* o1 = (u16*)(ws + 117702656);        // (2048,32,512)
    u16* o2 = (u16*)(ws + 184811520);        // (2048,4096)

    const dim3 blk(256);

    // ---- weight prep ----
    transpose_b16<float><<<dim3(48, 128, 1), blk, 0, stream>>>(wq_a, wq_a_t, 4096, 1536, 1536, 4096, 0, 0);
    transpose_b16<float><<<dim3(192, 48, 1), blk, 0, stream>>>(wq_b, wq_b_t, 1536, 6144, 6144, 1536, 0, 0);
    transpose_b16<float><<<dim3(18, 128, 1), blk, 0, stream>>>(wkva, wkva_t, 4096, 576, 576, 4096, 0, 0);
    transpose_b16<float><<<dim3(16, 4, 32), blk, 0, stream>>>(wkvb, wkbn_t, 128, 512, 512, 128, 256 * 512, 512 * 128);
    conv_b16<<<dim3(128, 1, 32), blk, 0, stream>>>(wkvb + 128 * 512, wkbv, 512, 512, 512, 256 * 512, 128 * 512);
    transpose_b16<float><<<dim3(128, 128, 1), blk, 0, stream>>>(wo, wo_t, 4096, 4096, 4096, 4096, 0, 0);
    conv_b16<<<dim3(2048, 1, 1), blk, 0, stream>>>(x, xb, 4096, 4096, 4096, 0, 0);

    // ---- s1: latent projections ----
    gemm_bt<0><<<dim3(12, 16, 1), blk, 0, stream>>>(xb, wq_a_t, q_lat, 4096, 4096, 4096, 1536,
                                                    0, 0, 0, 0, 0, 0);
    gemm_bt<0><<<dim3(5, 16, 1), blk, 0, stream>>>(xb, wkva_t, kvf, 4096, 4096, 4096, 640,
                                                   0, 0, 0, 0, 0, 0);
    // ---- norms + rope_k + kv transpose ----
    rmsnorm_b16<<<2048, blk, 0, stream>>>(q_lat, qnw, qn, 1536, 1536, 1536);
    rmsnorm_b16<<<2048, blk, 0, stream>>>(kvf, kvnw, kcat, 512, 640, 576);
    rope_k_kernel<<<256, blk, 0, stream>>>(kvf, fc, kcat);
    transpose_b16<u16><<<dim3(16, 32, 2), blk, 0, stream>>>(kcat, kvn_t, 1024, 512, 576, 1024,
                                                            (long)1024 * 576, (long)512 * 1024);
    // ---- s2: q = qn @ wq_b^T ----
    gemm_bt<1><<<dim3(48, 16, 1), blk, 0, stream>>>(qn, wq_b_t, q, 1536, 1536, 1536, 6144,
                                                    0, 0, 0, 0, 0, 0);
    // ---- s3: q_abs per head + rope_q -> qcat ----
    gemm_bt<1><<<dim3(4, 16, 32), blk, 0, stream>>>(q, wkbn_t, qcat, 128, 6144, 128, 18432,
                                                    0, 192, 0, (long)512 * 128, 0, 576);
    rope_q_kernel<<<8192, blk, 0, stream>>>(q, fc, qcat);
    // ---- fused causal flash attention v2: 512 threads, TK=128, LPT order ----
    flash_attn<<<dim3(32, 1, 64), dim3(512), 0, stream>>>(qcat, kcat, kvn_t, o1);
    // ---- s6: o2 = o1 @ wkv_b_v^T per head ----
    gemm_bt<1><<<dim3(1, 16, 32), blk, 0, stream>>>(o1, wkbv, o2, 512, 16384, 512, 4096,
                                                    0, 512, 0, (long)128 * 512, 0, 128);
    // ---- s7: out = o2 @ wo^T ----
    gemm_bt<0><<<dim3(32, 16, 1), blk, 0, stream>>>(o2, wo_t, out, 4096, 4096, 4096, 4096,
                                                    0, 0, 0, 0, 0, 0);
    (void)in_sizes; (void)n_in; (void)out_size; (void)d_in;
}